// Round 7
// baseline (1841643.945 us; speedup 1.0000x reference)
//
#include <hip/hip_runtime.h>
#include <stdint.h>

typedef unsigned int uint32;
typedef unsigned long long uint64;

#define T_SEQ 8192
#define NWG_L 128
#define BLK   320          // 4 compute waves + 1 hub/idle wave

// LDS byte offsets
#define OFF_WIH0  65536    // L0 only: Wih0 32x608B
#define OFF_BIAS  131072   // f32 [32]
#define OFF_DONE  131200
#define LDS_BYTES 131264

// ---------------- device helpers ----------------
__device__ __forceinline__ float bflo(uint32 u){ return __uint_as_float(u << 16); }
__device__ __forceinline__ float bfhi(uint32 u){ return __uint_as_float(u & 0xffff0000u); }

__device__ __forceinline__ unsigned short f2bf(float f){
  uint32 u = __float_as_uint(f);
  u += 0x7fffu + ((u >> 16) & 1u);          // round-to-nearest-even
  return (unsigned short)(u >> 16);
}

__device__ __forceinline__ void mac8(float& a, uint4 w,
    float h0,float h1,float h2,float h3,float h4,float h5,float h6,float h7){
  a = fmaf(bflo(w.x), h0, a); a = fmaf(bfhi(w.x), h1, a);
  a = fmaf(bflo(w.y), h2, a); a = fmaf(bfhi(w.y), h3, a);
  a = fmaf(bflo(w.z), h4, a); a = fmaf(bfhi(w.z), h5, a);
  a = fmaf(bflo(w.w), h6, a); a = fmaf(bfhi(w.w), h7, a);
}

__device__ __forceinline__ uint64 ald64(const uint64* p){
  return __hip_atomic_load(p, __ATOMIC_RELAXED, __HIP_MEMORY_SCOPE_AGENT);
}
__device__ __forceinline__ void ast64(uint64* p, uint64 v){
  __hip_atomic_store(p, v, __ATOMIC_RELAXED, __HIP_MEMORY_SCOPE_AGENT);
}
__device__ __forceinline__ uint32 ald32(const uint32* p){
  return __hip_atomic_load(p, __ATOMIC_RELAXED, __HIP_MEMORY_SCOPE_AGENT);
}
__device__ __forceinline__ void ast32(uint32* p, uint32 v){
  __hip_atomic_store(p, v, __ATOMIC_RELAXED, __HIP_MEMORY_SCOPE_AGENT);
}
__device__ __forceinline__ float val_of(uint64 w){ return __uint_as_float((uint32)(w >> 32)); }

// 16x 8B loads, bypass L1 / hit local-XCD L2 (sc0). L0 pattern: byte k*512 + voff,
// split across two saddr bases (13-bit signed imm limit). Includes vmcnt(0).
__device__ __forceinline__ void ld16b(const uint64* s0, const uint64* s1,
                                      uint32 voffB, uint64* u){
  asm volatile(
    "global_load_dwordx2 %0, %16, %17 sc0\n\t"
    "global_load_dwordx2 %1, %16, %17 offset:512 sc0\n\t"
    "global_load_dwordx2 %2, %16, %17 offset:1024 sc0\n\t"
    "global_load_dwordx2 %3, %16, %17 offset:1536 sc0\n\t"
    "global_load_dwordx2 %4, %16, %17 offset:2048 sc0\n\t"
    "global_load_dwordx2 %5, %16, %17 offset:2560 sc0\n\t"
    "global_load_dwordx2 %6, %16, %17 offset:3072 sc0\n\t"
    "global_load_dwordx2 %7, %16, %17 offset:3584 sc0\n\t"
    "global_load_dwordx2 %8, %16, %18 sc0\n\t"
    "global_load_dwordx2 %9, %16, %18 offset:512 sc0\n\t"
    "global_load_dwordx2 %10, %16, %18 offset:1024 sc0\n\t"
    "global_load_dwordx2 %11, %16, %18 offset:1536 sc0\n\t"
    "global_load_dwordx2 %12, %16, %18 offset:2048 sc0\n\t"
    "global_load_dwordx2 %13, %16, %18 offset:2560 sc0\n\t"
    "global_load_dwordx2 %14, %16, %18 offset:3072 sc0\n\t"
    "global_load_dwordx2 %15, %16, %18 offset:3584 sc0\n\t"
    "s_waitcnt vmcnt(0)"
    : "=&v"(u[0]), "=&v"(u[1]), "=&v"(u[2]), "=&v"(u[3]),
      "=&v"(u[4]), "=&v"(u[5]), "=&v"(u[6]), "=&v"(u[7]),
      "=&v"(u[8]), "=&v"(u[9]), "=&v"(u[10]), "=&v"(u[11]),
      "=&v"(u[12]), "=&v"(u[13]), "=&v"(u[14]), "=&v"(u[15])
    : "v"(voffB), "s"(s0), "s"(s1)
    : "memory");
}

// L1 pattern: bytes k*512 and k*512+256 off one base (max 3840 < 4096).
__device__ __forceinline__ void ld16a(const uint64* s0, uint32 voffB, uint64* u){
  asm volatile(
    "global_load_dwordx2 %0, %16, %17 sc0\n\t"
    "global_load_dwordx2 %1, %16, %17 offset:512 sc0\n\t"
    "global_load_dwordx2 %2, %16, %17 offset:1024 sc0\n\t"
    "global_load_dwordx2 %3, %16, %17 offset:1536 sc0\n\t"
    "global_load_dwordx2 %4, %16, %17 offset:2048 sc0\n\t"
    "global_load_dwordx2 %5, %16, %17 offset:2560 sc0\n\t"
    "global_load_dwordx2 %6, %16, %17 offset:3072 sc0\n\t"
    "global_load_dwordx2 %7, %16, %17 offset:3584 sc0\n\t"
    "global_load_dwordx2 %8, %16, %17 offset:256 sc0\n\t"
    "global_load_dwordx2 %9, %16, %17 offset:768 sc0\n\t"
    "global_load_dwordx2 %10, %16, %17 offset:1280 sc0\n\t"
    "global_load_dwordx2 %11, %16, %17 offset:1792 sc0\n\t"
    "global_load_dwordx2 %12, %16, %17 offset:2304 sc0\n\t"
    "global_load_dwordx2 %13, %16, %17 offset:2816 sc0\n\t"
    "global_load_dwordx2 %14, %16, %17 offset:3328 sc0\n\t"
    "global_load_dwordx2 %15, %16, %17 offset:3840 sc0\n\t"
    "s_waitcnt vmcnt(0)"
    : "=&v"(u[0]), "=&v"(u[1]), "=&v"(u[2]), "=&v"(u[3]),
      "=&v"(u[4]), "=&v"(u[5]), "=&v"(u[6]), "=&v"(u[7]),
      "=&v"(u[8]), "=&v"(u[9]), "=&v"(u[10]), "=&v"(u[11]),
      "=&v"(u[12]), "=&v"(u[13]), "=&v"(u[14]), "=&v"(u[15])
    : "v"(voffB), "s"(s0)
    : "memory");
}

// ---------------- persistent 2-layer LSTM, XCD-hub dataflow ----------------
// 256 WGs x 320 thr (1 WG/CU). Waves 0..3 compute (wave wv owns units 2wv,2wv+1,
// all 4 gates in-wave -> no step-loop barriers). Wave 4: per-XCD elected hub, or
// LDS-flag sleeper. Producers: tagged (fp32<<32)|(t+1) sc1 stores to global rings
// (h1 depth 16, h2 depth 4, spread idx ((u&15)<<6)|(u>>4)). Hubs (8 total = only
// fabric pollers) copy complete generations into per-XCD mailboxes (plain stores,
// live in local L2). Consumers poll mailbox with sc0 loads (local L2, no fabric);
// tags self-validate; fallback to direct sc1 ring poll after 256 local rounds.
extern "C" __global__ void __launch_bounds__(BLK)
lstm_persistent(const float* __restrict__ quote,
                const float* __restrict__ Wih0, const float* __restrict__ Whh0,
                const float* __restrict__ bih0, const float* __restrict__ bhh0,
                const float* __restrict__ Wih1, const float* __restrict__ Whh1,
                const float* __restrict__ bih1, const float* __restrict__ bhh1,
                uint64* __restrict__ h1r, uint64* __restrict__ h2r,
                uint64* __restrict__ mb1, uint64* __restrict__ mb2,
                uint32* __restrict__ claim, uint32* __restrict__ prog,
                float* __restrict__ h2last)
{
  extern __shared__ char smem[];
  float*  biasL = (float*)(smem + OFF_BIAS);
  uint32* dn    = (uint32*)(smem + OFF_DONE);

  const int tid = threadIdx.x;
  const int wv  = tid >> 6;          // 0..4
  const int c   = tid & 63;
  const int wg  = blockIdx.x;
  const bool isL1 = (wg >= NWG_L);
  const int lwg = isL1 ? (wg - NWG_L) : wg;
  const int unit_base = lwg * 8;

  uint32 xcd_raw;
  asm("s_getreg_b32 %0, hwreg(HW_REG_XCC_ID)" : "=s"(xcd_raw));
  const int xcd = (int)(xcd_raw & 7u);
  uint64* mb1x = mb1 + (size_t)xcd * 16 * 1024;
  uint64* mb2x = mb2 + (size_t)xcd * 4 * 1024;

  if (tid == 0) *dn = 0;

  // ---- one-time weight fill: fp32 global -> bf16 LDS (piece-interleaved) ----
  if (!isL1) {
    for (int gi = tid; gi < 4096; gi += BLK) {           // Whh0: 32 rows x 128 groups
      int r  = gi >> 7;
      int x0 = (gi & 127) << 3;
      int R  = (r >> 3) * 1024 + unit_base + (r & 7);
      const float* s = Whh0 + (size_t)R * 1024 + x0;
      unsigned short* d = (unsigned short*)(smem + r*2048 + ((x0>>3)&1)*1024 + (x0>>4)*16);
      #pragma unroll
      for (int m = 0; m < 8; ++m) d[m] = f2bf(s[m]);
    }
    for (int gi = tid; gi < 1216; gi += BLK) {           // Wih0: 32 rows x 38 groups
      int r  = gi / 38;
      int g  = gi - r * 38;
      int x0 = g << 3;
      int R  = (r >> 3) * 1024 + unit_base + (r & 7);
      unsigned short* d = (unsigned short*)(smem + OFF_WIH0 + r*608 + x0*2);
      #pragma unroll
      for (int m = 0; m < 8; ++m) {
        int x = x0 + m;
        d[m] = f2bf(x < 300 ? Wih0[(size_t)R * 300 + x] : 0.0f);
      }
    }
    if (tid < 32) {
      int R = (tid >> 3) * 1024 + unit_base + (tid & 7);
      biasL[tid] = bih0[R] + bhh0[R];
    }
  } else {
    for (int gi = tid; gi < 8192; gi += BLK) {           // concat: 32 rows x 256 groups
      int r  = gi >> 8;
      int x0 = (gi & 255) << 3;
      int R  = (r >> 3) * 1024 + unit_base + (r & 7);
      const float* s = (x0 < 1024) ? (Wih1 + (size_t)R*1024 + x0)
                                   : (Whh1 + (size_t)R*1024 + (x0 - 1024));
      int p  = x0 >> 9;
      int cs = (x0 & 511) >> 3;
      unsigned short* d = (unsigned short*)(smem + r*4096 + p*1024 + cs*16);
      #pragma unroll
      for (int m = 0; m < 8; ++m) d[m] = f2bf(s[m]);
    }
    if (tid < 32) {
      int R = (tid >> 3) * 1024 + unit_base + (tid & 7);
      biasL[tid] = bih1[R] + bhh1[R];
    }
  }
  __syncthreads();     // last barrier: step loop below is barrier-free

  if (wv == 4) {
    // ================= HUB (one per XCD, elected) or SLEEPER =================
    int hub = 0;
    if (c == 0)
      hub = (__hip_atomic_fetch_add(claim + xcd * 32, 1u,
                                    __ATOMIC_RELAXED, __HIP_MEMORY_SCOPE_AGENT) == 0u);
    hub = __shfl(hub, 0);
    if (hub) {
      int cur1 = 0, cur2 = 0;
      uint32 guard = 0;
      while ((cur1 < T_SEQ || cur2 < T_SEQ) && guard < 40000000u) {
        bool adv = false;
        if (cur1 < T_SEQ) {                  // capture h1 gen cur1 (tag cur1+1)
          const uint64* rs = h1r + (size_t)(cur1 & 15) * 1024;
          uint64 v[16]; bool ok = true;
          #pragma unroll
          for (int k = 0; k < 16; ++k) v[k] = ald64(rs + (k << 6) + c);
          uint32 want = (uint32)(cur1 + 1);
          #pragma unroll
          for (int k = 0; k < 16; ++k) ok &= ((uint32)v[k] == want);
          if (__all(ok)) {
            uint64* ds = mb1x + (size_t)(cur1 & 15) * 1024;
            #pragma unroll
            for (int k = 0; k < 16; ++k) ds[(k << 6) + c] = v[k];
            ++cur1; adv = true;
          }
        }
        if (cur2 < T_SEQ) {                  // capture h2 gen cur2 (tag cur2+1)
          const uint64* rs = h2r + (size_t)(cur2 & 3) * 1024;
          uint64 v[16]; bool ok = true;
          #pragma unroll
          for (int k = 0; k < 16; ++k) v[k] = ald64(rs + (k << 6) + c);
          uint32 want = (uint32)(cur2 + 1);
          #pragma unroll
          for (int k = 0; k < 16; ++k) ok &= ((uint32)v[k] == want);
          if (__all(ok)) {
            uint64* ds = mb2x + (size_t)(cur2 & 3) * 1024;
            #pragma unroll
            for (int k = 0; k < 16; ++k) ds[(k << 6) + c] = v[k];
            ++cur2; adv = true;
          }
        }
        if (!adv) { __builtin_amdgcn_s_sleep(1); ++guard; }
      }
    } else {
      while (__hip_atomic_load(dn, __ATOMIC_RELAXED, __HIP_MEMORY_SCOPE_WORKGROUP) == 0u)
        __builtin_amdgcn_s_sleep(100);
    }
    return;
  }

  // ========================= COMPUTE WAVES (wv 0..3) =========================
  float bA0 = biasL[0*8+2*wv],   bA1 = biasL[1*8+2*wv],
        bA2 = biasL[2*8+2*wv],   bA3 = biasL[3*8+2*wv];
  float bB0 = biasL[0*8+2*wv+1], bB1 = biasL[1*8+2*wv+1],
        bB2 = biasL[2*8+2*wv+1], bB3 = biasL[3*8+2*wv+1];

  float cstA = 0.0f, cstB = 0.0f;
  uint32 prog_seen = 0;

  for (int t = 0; t < T_SEQ; ++t) {
    float acc[8];
    #pragma unroll
    for (int i = 0; i < 8; ++i) acc[i] = 0.0f;

    if (!isL1) {
      // ---- x-part from LDS (independent of recurrence) ----
      if (c < 38) {
        float xv[8];
        int x0 = c << 3;
        const float* xr = quote + (size_t)t * 300 + x0;
        #pragma unroll
        for (int m = 0; m < 8; ++m) xv[m] = (x0 + m < 300) ? xr[m] : 0.0f;
        #pragma unroll
        for (int g = 0; g < 4; ++g)
          #pragma unroll
          for (int j = 0; j < 2; ++j) {
            int r = g*8 + 2*wv + j;
            uint4 w = *(const uint4*)(smem + OFF_WIH0 + r*608 + (c << 4));
            mac8(acc[g*2+j], w, xv[0],xv[1],xv[2],xv[3],xv[4],xv[5],xv[6],xv[7]);
          }
      }
      if (t > 0) {
        // ---- h1[t-1] via local mailbox (sc0, lane c <- h[c*16+k]) ----
        const uint32 want = (uint32)t;
        const uint64* ms = mb1x + (size_t)((t-1) & 15) * 1024;
        uint64 up[16];
        ld16b(ms, ms + 512, (uint32)(c << 3), up);
        uint32 rounds = 0; bool ok;
        for (;;) {
          ok = true;
          #pragma unroll
          for (int k = 0; k < 16; ++k) ok &= ((uint32)up[k] == want);
          if (__all(ok)) break;
          if (++rounds > 256u) break;
          __builtin_amdgcn_s_sleep(1);
          ld16b(ms, ms + 512, (uint32)(c << 3), up);
        }
        if (!__all(ok)) {                     // fallback: direct sc1 ring poll
          const uint64* hb = h1r + (size_t)((t-1) & 15) * 1024;
          uint32 guard = 0;
          for (;;) {
            #pragma unroll
            for (int k = 0; k < 16; ++k) up[k] = ald64(hb + (k << 6) + c);
            bool ok2 = true;
            #pragma unroll
            for (int k = 0; k < 16; ++k) ok2 &= ((uint32)up[k] == want);
            if (__all(ok2)) break;
            __builtin_amdgcn_s_sleep(2);
            if (++guard > 20000000u) break;
          }
        }
        #pragma unroll
        for (int g = 0; g < 4; ++g)
          #pragma unroll
          for (int j = 0; j < 2; ++j) {
            int r = g*8 + 2*wv + j;
            const char* rowb = smem + r*2048;
            uint4 w0 = *(const uint4*)(rowb + (c << 4));
            uint4 w1 = *(const uint4*)(rowb + 1024 + (c << 4));
            mac8(acc[g*2+j], w0, val_of(up[0]),val_of(up[1]),val_of(up[2]),val_of(up[3]),
                              val_of(up[4]),val_of(up[5]),val_of(up[6]),val_of(up[7]));
            mac8(acc[g*2+j], w1, val_of(up[8]),val_of(up[9]),val_of(up[10]),val_of(up[11]),
                              val_of(up[12]),val_of(up[13]),val_of(up[14]),val_of(up[15]));
          }
      }
    } else {
      // lane c <- h[c*8+k], h[512+c*8+k]; mailbox idx vbase+k*64 (+32)
      const int vbase = ((c & 1) << 9) + (c >> 1);
      const uint32 voffB = (uint32)(vbase << 3);
      uint64 ub[16], ua[16];

      // ---- phase B: Wih1 * h1[t] (want tag t+1; L0 runs ahead) ----
      {
        const uint32 want = (uint32)(t + 1);
        const uint64* ms = mb1x + (size_t)(t & 15) * 1024;
        ld16a(ms, voffB, ub);
        uint32 rounds = 0; bool ok;
        for (;;) {
          ok = true;
          #pragma unroll
          for (int k = 0; k < 16; ++k) ok &= ((uint32)ub[k] == want);
          if (__all(ok)) break;
          if (++rounds > 256u) break;
          __builtin_amdgcn_s_sleep(1);
          ld16a(ms, voffB, ub);
        }
        if (!__all(ok)) {
          const uint64* hb = h1r + (size_t)(t & 15) * 1024;
          uint32 guard = 0;
          for (;;) {
            #pragma unroll
            for (int k = 0; k < 8; ++k) {
              ub[k]   = ald64(hb + vbase + (k << 6));
              ub[8+k] = ald64(hb + vbase + (k << 6) + 32);
            }
            bool ok2 = true;
            #pragma unroll
            for (int k = 0; k < 16; ++k) ok2 &= ((uint32)ub[k] == want);
            if (__all(ok2)) break;
            __builtin_amdgcn_s_sleep(2);
            if (++guard > 20000000u) break;
          }
        }
        #pragma unroll
        for (int g = 0; g < 4; ++g)
          #pragma unroll
          for (int j = 0; j < 2; ++j) {
            int r = g*8 + 2*wv + j;
            const char* rowb = smem + r*4096;
            uint4 w0 = *(const uint4*)(rowb + (c << 4));
            uint4 w1 = *(const uint4*)(rowb + 1024 + (c << 4));
            mac8(acc[g*2+j], w0, val_of(ub[0]),val_of(ub[1]),val_of(ub[2]),val_of(ub[3]),
                              val_of(ub[4]),val_of(ub[5]),val_of(ub[6]),val_of(ub[7]));
            mac8(acc[g*2+j], w1, val_of(ub[8]),val_of(ub[9]),val_of(ub[10]),val_of(ub[11]),
                              val_of(ub[12]),val_of(ub[13]),val_of(ub[14]),val_of(ub[15]));
          }
      }
      // ---- phase A: Whh1 * h2[t-1] (want tag t; self-layer pace-setter) ----
      if (t > 0) {
        const uint32 want = (uint32)t;
        const uint64* ms = mb2x + (size_t)((t-1) & 3) * 1024;
        ld16a(ms, voffB, ua);
        uint32 rounds = 0; bool ok;
        for (;;) {
          ok = true;
          #pragma unroll
          for (int k = 0; k < 16; ++k) ok &= ((uint32)ua[k] == want);
          if (__all(ok)) break;
          if (++rounds > 256u) break;
          __builtin_amdgcn_s_sleep(1);
          ld16a(ms, voffB, ua);
        }
        if (!__all(ok)) {
          const uint64* hb = h2r + (size_t)((t-1) & 3) * 1024;
          uint32 guard = 0;
          for (;;) {
            #pragma unroll
            for (int k = 0; k < 8; ++k) {
              ua[k]   = ald64(hb + vbase + (k << 6));
              ua[8+k] = ald64(hb + vbase + (k << 6) + 32);
            }
            bool ok2 = true;
            #pragma unroll
            for (int k = 0; k < 16; ++k) ok2 &= ((uint32)ua[k] == want);
            if (__all(ok2)) break;
            __builtin_amdgcn_s_sleep(2);
            if (++guard > 20000000u) break;
          }
        }
        #pragma unroll
        for (int g = 0; g < 4; ++g)
          #pragma unroll
          for (int j = 0; j < 2; ++j) {
            int r = g*8 + 2*wv + j;
            const char* rowb = smem + r*4096;
            uint4 w2 = *(const uint4*)(rowb + 2048 + (c << 4));
            uint4 w3 = *(const uint4*)(rowb + 3072 + (c << 4));
            mac8(acc[g*2+j], w2, val_of(ua[0]),val_of(ua[1]),val_of(ua[2]),val_of(ua[3]),
                              val_of(ua[4]),val_of(ua[5]),val_of(ua[6]),val_of(ua[7]));
            mac8(acc[g*2+j], w3, val_of(ua[8]),val_of(ua[9]),val_of(ua[10]),val_of(ua[11]),
                              val_of(ua[12]),val_of(ua[13]),val_of(ua[14]),val_of(ua[15]));
          }
      }
    }

    // ---- full butterfly: every lane ends with all 8 row totals ----
    #pragma unroll
    for (int i = 0; i < 8; ++i) {
      #pragma unroll
      for (int m = 1; m < 64; m <<= 1) acc[i] += __shfl_xor(acc[i], m);
    }
    // ---- gates (lane-uniform), units A=2wv, B=2wv+1 ----
    float gA0 = acc[0] + bA0, gA1 = acc[2] + bA1, gA2 = acc[4] + bA2, gA3 = acc[6] + bA3;
    float iA = 1.0f/(1.0f+expf(-gA0)), fA = 1.0f/(1.0f+expf(-gA1));
    float gA = tanhf(gA2),             oA = 1.0f/(1.0f+expf(-gA3));
    cstA = fA*cstA + iA*gA;
    float hA = oA * tanhf(cstA);
    float gB0 = acc[1] + bB0, gB1 = acc[3] + bB1, gB2 = acc[5] + bB2, gB3 = acc[7] + bB3;
    float iB = 1.0f/(1.0f+expf(-gB0)), fB = 1.0f/(1.0f+expf(-gB1));
    float gB = tanhf(gB2),             oB = 1.0f/(1.0f+expf(-gB3));
    cstB = fB*cstB + iB*gB;
    float hB = oB * tanhf(cstB);

    // ---- tagged publish (lanes 0,1 per wave), sc1 to global ring ----
    if (!isL1) {
      if ((int)prog_seen < t - 12) {       // ring back-pressure (rarely taken)
        uint32 guard = 0;
        for (;;) {
          uint32 p = ald32(prog);
          if ((int)p >= t - 12) { prog_seen = p; break; }
          __builtin_amdgcn_s_sleep(2);
          if (++guard > 20000000u) break;
        }
      }
      if (c < 2) {
        int u = unit_base + 2*wv + c;
        int v = ((u & 15) << 6) | (u >> 4);
        float h = c ? hB : hA;
        ast64(h1r + (size_t)(t & 15) * 1024 + v,
              ((uint64)__float_as_uint(h) << 32) | (uint32)(t + 1));
      }
    } else {
      if (c < 2) {
        int u = unit_base + 2*wv + c;
        int v = ((u & 15) << 6) | (u >> 4);
        float h = c ? hB : hA;
        ast64(h2r + (size_t)(t & 3) * 1024 + v,
              ((uint64)__float_as_uint(h) << 32) | (uint32)(t + 1));
        if (t == T_SEQ - 1) h2last[u] = h;
      }
      if (c == 0 && lwg == 0 && wv == 0) ast32(prog, (uint32)(t + 1));
    }
    if (t == T_SEQ - 1 && c == 0)
      __hip_atomic_store(dn, 1u, __ATOMIC_RELAXED, __HIP_MEMORY_SCOPE_WORKGROUP);
  }
}

// ---------------- tiny MLP head ----------------
extern "C" __global__ void __launch_bounds__(256)
head_fc(const float* __restrict__ W, const float* __restrict__ b,
        const float* __restrict__ xin, float* __restrict__ y, int n_in)
{
  __shared__ float sred[256];
  const int i = blockIdx.x;
  float p = 0.0f;
  for (int k = threadIdx.x; k < n_in; k += 256)
    p = fmaf(W[(size_t)i * n_in + k], xin[k], p);
  sred[threadIdx.x] = p;
  __syncthreads();
  for (int s = 128; s > 0; s >>= 1) {
    if (threadIdx.x < s) sred[threadIdx.x] += sred[threadIdx.x + s];
    __syncthreads();
  }
  if (threadIdx.x == 0) y[i] = fmaxf(sred[0] + b[i], 0.0f);
}

extern "C" __global__ void __launch_bounds__(64)
head_out(const float* __restrict__ W2, const float* __restrict__ b2,
         const float* __restrict__ y1, float* __restrict__ out)
{
  const int l = threadIdx.x;
  float p0 = 0.0f, p1 = 0.0f, p2 = 0.0f;
  for (int k = l; k < 512; k += 64) {
    float v = y1[k];
    p0 = fmaf(W2[k],        v, p0);
    p1 = fmaf(W2[512 + k],  v, p1);
    p2 = fmaf(W2[1024 + k], v, p2);
  }
  #pragma unroll
  for (int m = 1; m < 64; m <<= 1) {
    p0 += __shfl_xor(p0, m);
    p1 += __shfl_xor(p1, m);
    p2 += __shfl_xor(p2, m);
  }
  if (l == 0) {
    float z0 = p0 + b2[0], z1 = p1 + b2[1], z2 = p2 + b2[2];
    float mx = fmaxf(z0, fmaxf(z1, z2));
    float lse = mx + logf(expf(z0 - mx) + expf(z1 - mx) + expf(z2 - mx));
    out[0] = z0 - lse; out[1] = z1 - lse; out[2] = z2 - lse;
  }
}

// ---------------- host ----------------
extern "C" void kernel_launch(void* const* d_in, const int* in_sizes, int n_in,
                              void* d_out, int out_size, void* d_ws, size_t ws_size,
                              hipStream_t stream)
{
  (void)in_sizes; (void)n_in; (void)out_size; (void)ws_size;
  const float* quote = (const float*)d_in[0];
  const float* Wih0  = (const float*)d_in[1];
  const float* Whh0  = (const float*)d_in[2];
  const float* bih0  = (const float*)d_in[3];
  const float* bhh0  = (const float*)d_in[4];
  const float* Wih1  = (const float*)d_in[5];
  const float* Whh1  = (const float*)d_in[6];
  const float* bih1  = (const float*)d_in[7];
  const float* bhh1  = (const float*)d_in[8];
  const float* W0    = (const float*)d_in[9];
  const float* b0    = (const float*)d_in[10];
  const float* W1    = (const float*)d_in[11];
  const float* b1    = (const float*)d_in[12];
  const float* W2    = (const float*)d_in[13];
  const float* b2    = (const float*)d_in[14];

  char* ws = (char*)d_ws;
  uint64* h1r    = (uint64*)(ws + 0);          // [16][1024] tagged fp32 (128 KB)
  uint64* h2r    = (uint64*)(ws + 131072);     // [4][1024]  tagged fp32 (32 KB)
  uint32* prog   = (uint32*)(ws + 163840);     // L1 progress watermark
  uint32* claim  = (uint32*)(ws + 163968);     // 8 x 128B hub-election slots
  uint64* mb1    = (uint64*)(ws + 164992);     // 8 XCD x [16][1024] mailbox (1 MB)
  uint64* mb2    = (uint64*)(ws + 1213568);    // 8 XCD x [4][1024]  mailbox (256 KB)
  float*  h2last = (float*)(ws + 1475712);     // 1024 f32
  float*  y0     = (float*)(ws + 1479808);     // 512 f32
  float*  y1     = (float*)(ws + 1481856);     // 512 f32

  hipMemsetAsync(ws, 0, 1475712, stream);      // rings + prog + claim + mailboxes

  hipFuncSetAttribute((const void*)lstm_persistent,
                      hipFuncAttributeMaxDynamicSharedMemorySize, LDS_BYTES);

  void* args[] = { (void*)&quote, (void*)&Wih0, (void*)&Whh0, (void*)&bih0, (void*)&bhh0,
                   (void*)&Wih1, (void*)&Whh1, (void*)&bih1, (void*)&bhh1,
                   (void*)&h1r, (void*)&h2r, (void*)&mb1, (void*)&mb2,
                   (void*)&claim, (void*)&prog, (void*)&h2last };
  hipLaunchCooperativeKernel((const void*)lstm_persistent, dim3(256), dim3(BLK),
                             args, (uint32)LDS_BYTES, stream);

  head_fc<<<512, 256, 0, stream>>>(W0, b0, h2last, y0, 1024);
  head_fc<<<512, 256, 0, stream>>>(W1, b1, y0, y1, 512);
  head_out<<<1, 64, 0, stream>>>(W2, b2, y1, (float*)d_out);
}

// Round 10
// 65707.129 us; speedup vs baseline: 28.0281x; 28.0281x over previous
//
#include <hip/hip_runtime.h>
#include <stdint.h>

typedef unsigned int uint32;
typedef unsigned long long uint64;

#define T_SEQ 8192
#define NWG_L 128

// LDS byte offsets
#define OFF_WIH0  65536            // L0 only: Wih0 32x608B
#define OFF_BIAS  131072           // f32 [32]
#define LDS_BYTES 131200

// ---------------- device helpers ----------------
__device__ __forceinline__ float bflo(uint32 u){ return __uint_as_float(u << 16); }
__device__ __forceinline__ float bfhi(uint32 u){ return __uint_as_float(u & 0xffff0000u); }

__device__ __forceinline__ unsigned short f2bf(float f){
  uint32 u = __float_as_uint(f);
  u += 0x7fffu + ((u >> 16) & 1u);          // round-to-nearest-even
  return (unsigned short)(u >> 16);
}

__device__ __forceinline__ void mac8(float& a, uint4 w,
    float h0,float h1,float h2,float h3,float h4,float h5,float h6,float h7){
  a = fmaf(bflo(w.x), h0, a); a = fmaf(bfhi(w.x), h1, a);
  a = fmaf(bflo(w.y), h2, a); a = fmaf(bfhi(w.y), h3, a);
  a = fmaf(bflo(w.z), h4, a); a = fmaf(bfhi(w.z), h5, a);
  a = fmaf(bflo(w.w), h6, a); a = fmaf(bfhi(w.w), h7, a);
}

__device__ __forceinline__ uint64 ald64(const uint64* p){
  return __hip_atomic_load(p, __ATOMIC_RELAXED, __HIP_MEMORY_SCOPE_AGENT);
}
__device__ __forceinline__ void ast64(uint64* p, uint64 v){
  __hip_atomic_store(p, v, __ATOMIC_RELAXED, __HIP_MEMORY_SCOPE_AGENT);
}
__device__ __forceinline__ uint32 ald32(const uint32* p){
  return __hip_atomic_load(p, __ATOMIC_RELAXED, __HIP_MEMORY_SCOPE_AGENT);
}
__device__ __forceinline__ void ast32(uint32* p, uint32 v){
  __hip_atomic_store(p, v, __ATOMIC_RELAXED, __HIP_MEMORY_SCOPE_AGENT);
}
__device__ __forceinline__ float val_of(uint64 w){ return __uint_as_float((uint32)(w >> 32)); }

// ---------------- persistent 2-layer LSTM: R5 skeleton + in-wave gates ----------------
// 256 WGs x 256 thr (1 WG/CU). WG 0..127: layer0 (8 units each); 128..255: layer1.
// Ring word for unit u at spread(u)=((u&15)<<6)|(u>>4), value (fp32(h)<<32)|(t+1),
// one relaxed agent 8B atomic (sc1). Consumer polls are wave-coalesced (proven R5).
// Wave wv owns units 2wv,2wv+1 (rows g*8+2wv+j): full butterfly + lane-uniform gates
// + per-wave publish -> NO barriers / LDS red[] in the step loop (proven R4/R6).
// h1 ring 16 deep, h2 ring 4 deep; L0 overwrite of gen t-16 gated by prog >= t-12.
extern "C" __global__ void __launch_bounds__(256)
lstm_persistent(const float* __restrict__ quote,
                const float* __restrict__ Wih0, const float* __restrict__ Whh0,
                const float* __restrict__ bih0, const float* __restrict__ bhh0,
                const float* __restrict__ Wih1, const float* __restrict__ Whh1,
                const float* __restrict__ bih1, const float* __restrict__ bhh1,
                uint64* __restrict__ h1r, uint64* __restrict__ h2r,
                uint32* __restrict__ prog, float* __restrict__ h2last)
{
  extern __shared__ char smem[];
  float* biasL = (float*)(smem + OFF_BIAS);

  const int tid = threadIdx.x;
  const int wv  = tid >> 6;          // 0..3
  const int c   = tid & 63;
  const int wg  = blockIdx.x;
  const bool isL1 = (wg >= NWG_L);
  const int lwg = isL1 ? (wg - NWG_L) : wg;
  const int unit_base = lwg * 8;

  // ---- one-time weight fill: fp32 global -> bf16 LDS (piece-interleaved, as R5) ----
  if (!isL1) {
    for (int gi = tid; gi < 4096; gi += 256) {           // Whh0: 32 rows x 128 groups
      int r  = gi >> 7;
      int x0 = (gi & 127) << 3;
      int R  = (r >> 3) * 1024 + unit_base + (r & 7);
      const float* s = Whh0 + (size_t)R * 1024 + x0;
      unsigned short* d = (unsigned short*)(smem + r*2048 + ((x0>>3)&1)*1024 + (x0>>4)*16);
      #pragma unroll
      for (int m = 0; m < 8; ++m) d[m] = f2bf(s[m]);
    }
    for (int gi = tid; gi < 1216; gi += 256) {           // Wih0: 32 rows x 38 groups
      int r  = gi / 38;
      int g  = gi - r * 38;
      int x0 = g << 3;
      int R  = (r >> 3) * 1024 + unit_base + (r & 7);
      unsigned short* d = (unsigned short*)(smem + OFF_WIH0 + r*608 + x0*2);
      #pragma unroll
      for (int m = 0; m < 8; ++m) {
        int x = x0 + m;
        d[m] = f2bf(x < 300 ? Wih0[(size_t)R * 300 + x] : 0.0f);
      }
    }
    if (tid < 32) {
      int R = (tid >> 3) * 1024 + unit_base + (tid & 7);
      biasL[tid] = bih0[R] + bhh0[R];
    }
  } else {
    for (int gi = tid; gi < 8192; gi += 256) {           // concat: 32 rows x 256 groups
      int r  = gi >> 8;
      int x0 = (gi & 255) << 3;                          // concat col 0..2047
      int R  = (r >> 3) * 1024 + unit_base + (r & 7);
      const float* s = (x0 < 1024) ? (Wih1 + (size_t)R*1024 + x0)
                                   : (Whh1 + (size_t)R*1024 + (x0 - 1024));
      int p  = x0 >> 9;
      int cs = (x0 & 511) >> 3;
      unsigned short* d = (unsigned short*)(smem + r*4096 + p*1024 + cs*16);
      #pragma unroll
      for (int m = 0; m < 8; ++m) d[m] = f2bf(s[m]);
    }
    if (tid < 32) {
      int R = (tid >> 3) * 1024 + unit_base + (tid & 7);
      biasL[tid] = bih1[R] + bhh1[R];
    }
  }
  __syncthreads();    // last barrier: step loop below is barrier-free

  // per-wave biases for rows g*8 + 2wv + {0,1} (lane-uniform scalars)
  const float bA0 = biasL[0*8+2*wv],   bA1 = biasL[1*8+2*wv],
              bA2 = biasL[2*8+2*wv],   bA3 = biasL[3*8+2*wv];
  const float bB0 = biasL[0*8+2*wv+1], bB1 = biasL[1*8+2*wv+1],
              bB2 = biasL[2*8+2*wv+1], bB3 = biasL[3*8+2*wv+1];

  float cstA = 0.0f, cstB = 0.0f;
  uint32 prog_seen = 0;

  for (int t = 0; t < T_SEQ; ++t) {
    float acc[8];
    #pragma unroll
    for (int i = 0; i < 8; ++i) acc[i] = 0.0f;

    if (!isL1) {
      // ---- issue h1[t-1] loads early (coalesced: ring[k*64+c] == h[c*16+k]) ----
      uint64 up[16];
      const uint64* hb = h1r + (size_t)((t-1) & 15) * 1024;
      if (t > 0) {
        #pragma unroll
        for (int k = 0; k < 16; ++k) up[k] = ald64(hb + (k << 6) + c);
      }
      // ---- x-part (independent of recurrence; hides data-load latency) ----
      if (c < 38) {
        float xv[8];
        int x0 = c << 3;
        const float* xr = quote + (size_t)t * 300 + x0;
        #pragma unroll
        for (int m = 0; m < 8; ++m) xv[m] = (x0 + m < 300) ? xr[m] : 0.0f;
        #pragma unroll
        for (int g = 0; g < 4; ++g)
          #pragma unroll
          for (int j = 0; j < 2; ++j) {
            int r = g*8 + 2*wv + j;
            uint4 w = *(const uint4*)(smem + OFF_WIH0 + r*608 + (c << 4));
            mac8(acc[g*2+j], w, xv[0],xv[1],xv[2],xv[3],xv[4],xv[5],xv[6],xv[7]);
          }
      }
      if (t > 0) {
        const uint32 want = (uint32)t;
        bool ok = true;
        #pragma unroll
        for (int k = 0; k < 16; ++k) ok &= ((uint32)up[k] == want);
        if (!__all(ok)) {
          uint32 guard = 0;
          for (;;) {
            #pragma unroll
            for (int k = 0; k < 16; ++k) up[k] = ald64(hb + (k << 6) + c);
            bool ok2 = true;
            #pragma unroll
            for (int k = 0; k < 16; ++k) ok2 &= ((uint32)up[k] == want);
            if (__all(ok2)) break;
            __builtin_amdgcn_s_sleep(1);
            if (++guard > 20000000u) break;      // bug -> garbage, not hang
          }
        }
        #pragma unroll
        for (int g = 0; g < 4; ++g)
          #pragma unroll
          for (int j = 0; j < 2; ++j) {
            int r = g*8 + 2*wv + j;
            const char* rowb = smem + r*2048;
            uint4 w0 = *(const uint4*)(rowb + (c << 4));
            uint4 w1 = *(const uint4*)(rowb + 1024 + (c << 4));
            mac8(acc[g*2+j], w0, val_of(up[0]),val_of(up[1]),val_of(up[2]),val_of(up[3]),
                              val_of(up[4]),val_of(up[5]),val_of(up[6]),val_of(up[7]));
            mac8(acc[g*2+j], w1, val_of(up[8]),val_of(up[9]),val_of(up[10]),val_of(up[11]),
                              val_of(up[12]),val_of(up[13]),val_of(up[14]),val_of(up[15]));
          }
      }
    } else {
      // Lane c needs h[c*8+k], h[512+c*8+k]: ring idx vbase+k*64, +32 (proven R5)
      const int vbase = ((c & 1) << 9) + (c >> 1);
      uint64 ua[16], ub[16];
      const uint64* h2b = h2r + (size_t)((t-1) & 3) * 1024;
      const uint64* h1b = h1r + (size_t)(t & 15) * 1024;
      if (t > 0) {
        #pragma unroll
        for (int k = 0; k < 8; ++k) {
          ua[k]   = ald64(h2b + vbase + (k << 6));
          ua[8+k] = ald64(h2b + vbase + (k << 6) + 32);
        }
      }
      #pragma unroll
      for (int k = 0; k < 8; ++k) {
        ub[k]   = ald64(h1b + vbase + (k << 6));
        ub[8+k] = ald64(h1b + vbase + (k << 6) + 32);
      }

      // ---- phase B first: Wih1 * h1[t] (L0 runs ahead -> usually instant) ----
      {
        const uint32 want = (uint32)(t + 1);
        bool ok = true;
        #pragma unroll
        for (int k = 0; k < 16; ++k) ok &= ((uint32)ub[k] == want);
        if (!__all(ok)) {
          uint32 guard = 0;
          for (;;) {
            #pragma unroll
            for (int k = 0; k < 8; ++k) {
              ub[k]   = ald64(h1b + vbase + (k << 6));
              ub[8+k] = ald64(h1b + vbase + (k << 6) + 32);
            }
            bool ok2 = true;
            #pragma unroll
            for (int k = 0; k < 16; ++k) ok2 &= ((uint32)ub[k] == want);
            if (__all(ok2)) break;
            __builtin_amdgcn_s_sleep(1);
            if (++guard > 20000000u) break;
          }
        }
        #pragma unroll
        for (int g = 0; g < 4; ++g)
          #pragma unroll
          for (int j = 0; j < 2; ++j) {
            int r = g*8 + 2*wv + j;
            const char* rowb = smem + r*4096;
            uint4 w0 = *(const uint4*)(rowb + (c << 4));
            uint4 w1 = *(const uint4*)(rowb + 1024 + (c << 4));
            mac8(acc[g*2+j], w0, val_of(ub[0]),val_of(ub[1]),val_of(ub[2]),val_of(ub[3]),
                              val_of(ub[4]),val_of(ub[5]),val_of(ub[6]),val_of(ub[7]));
            mac8(acc[g*2+j], w1, val_of(ub[8]),val_of(ub[9]),val_of(ub[10]),val_of(ub[11]),
                              val_of(ub[12]),val_of(ub[13]),val_of(ub[14]),val_of(ub[15]));
          }
      }
      // ---- phase A: Whh1 * h2[t-1] (self-layer pace-setter) ----
      if (t > 0) {
        const uint32 want = (uint32)t;
        bool ok = true;
        #pragma unroll
        for (int k = 0; k < 16; ++k) ok &= ((uint32)ua[k] == want);
        if (!__all(ok)) {
          uint32 guard = 0;
          for (;;) {
            #pragma unroll
            for (int k = 0; k < 8; ++k) {
              ua[k]   = ald64(h2b + vbase + (k << 6));
              ua[8+k] = ald64(h2b + vbase + (k << 6) + 32);
            }
            bool ok2 = true;
            #pragma unroll
            for (int k = 0; k < 16; ++k) ok2 &= ((uint32)ua[k] == want);
            if (__all(ok2)) break;
            __builtin_amdgcn_s_sleep(1);
            if (++guard > 20000000u) break;
          }
        }
        #pragma unroll
        for (int g = 0; g < 4; ++g)
          #pragma unroll
          for (int j = 0; j < 2; ++j) {
            int r = g*8 + 2*wv + j;
            const char* rowb = smem + r*4096;
            uint4 w2 = *(const uint4*)(rowb + 2048 + (c << 4));
            uint4 w3 = *(const uint4*)(rowb + 3072 + (c << 4));
            mac8(acc[g*2+j], w2, val_of(ua[0]),val_of(ua[1]),val_of(ua[2]),val_of(ua[3]),
                              val_of(ua[4]),val_of(ua[5]),val_of(ua[6]),val_of(ua[7]));
            mac8(acc[g*2+j], w3, val_of(ua[8]),val_of(ua[9]),val_of(ua[10]),val_of(ua[11]),
                              val_of(ua[12]),val_of(ua[13]),val_of(ua[14]),val_of(ua[15]));
          }
      }
    }

    // ---- full butterfly: every lane ends with all 8 row totals ----
    #pragma unroll
    for (int i = 0; i < 8; ++i) {
      #pragma unroll
      for (int m = 1; m < 64; m <<= 1) acc[i] += __shfl_xor(acc[i], m);
    }
    // ---- gates (lane-uniform), units A=2wv, B=2wv+1 ----
    float gA0 = acc[0] + bA0, gA1 = acc[2] + bA1, gA2 = acc[4] + bA2, gA3 = acc[6] + bA3;
    float iA = 1.0f/(1.0f+expf(-gA0)), fA = 1.0f/(1.0f+expf(-gA1));
    float gA = tanhf(gA2),             oA = 1.0f/(1.0f+expf(-gA3));
    cstA = fA*cstA + iA*gA;
    float hA = oA * tanhf(cstA);
    float gB0 = acc[1] + bB0, gB1 = acc[3] + bB1, gB2 = acc[5] + bB2, gB3 = acc[7] + bB3;
    float iB = 1.0f/(1.0f+expf(-gB0)), fB = 1.0f/(1.0f+expf(-gB1));
    float gB = tanhf(gB2),             oB = 1.0f/(1.0f+expf(-gB3));
    cstB = fB*cstB + iB*gB;
    float hB = oB * tanhf(cstB);

    // ---- per-wave tagged publish (lanes 0,1), sc1 to global ring ----
    if (!isL1) {
      if ((int)prog_seen < t - 12) {       // ring back-pressure (rarely taken)
        uint32 guard = 0;
        for (;;) {
          uint32 p = ald32(prog);
          if ((int)p >= t - 12) { prog_seen = p; break; }
          __builtin_amdgcn_s_sleep(2);
          if (++guard > 20000000u) break;
        }
      }
      if (c < 2) {
        int u = unit_base + 2*wv + c;
        int v = ((u & 15) << 6) | (u >> 4);
        float h = c ? hB : hA;
        ast64(h1r + (size_t)(t & 15) * 1024 + v,
              ((uint64)__float_as_uint(h) << 32) | (uint32)(t + 1));
      }
    } else {
      if (c < 2) {
        int u = unit_base + 2*wv + c;
        int v = ((u & 15) << 6) | (u >> 4);
        float h = c ? hB : hA;
        ast64(h2r + (size_t)(t & 3) * 1024 + v,
              ((uint64)__float_as_uint(h) << 32) | (uint32)(t + 1));
        if (t == T_SEQ - 1) h2last[u] = h;
      }
      if (c == 0 && lwg == 0 && wv == 0) ast32(prog, (uint32)(t + 1));
    }
  }
}

// ---------------- tiny MLP head ----------------
extern "C" __global__ void __launch_bounds__(256)
head_fc(const float* __restrict__ W, const float* __restrict__ b,
        const float* __restrict__ xin, float* __restrict__ y, int n_in)
{
  __shared__ float sred[256];
  const int i = blockIdx.x;
  float p = 0.0f;
  for (int k = threadIdx.x; k < n_in; k += 256)
    p = fmaf(W[(size_t)i * n_in + k], xin[k], p);
  sred[threadIdx.x] = p;
  __syncthreads();
  for (int s = 128; s > 0; s >>= 1) {
    if (threadIdx.x < s) sred[threadIdx.x] += sred[threadIdx.x + s];
    __syncthreads();
  }
  if (threadIdx.x == 0) y[i] = fmaxf(sred[0] + b[i], 0.0f);
}

extern "C" __global__ void __launch_bounds__(64)
head_out(const float* __restrict__ W2, const float* __restrict__ b2,
         const float* __restrict__ y1, float* __restrict__ out)
{
  const int l = threadIdx.x;
  float p0 = 0.0f, p1 = 0.0f, p2 = 0.0f;
  for (int k = l; k < 512; k += 64) {
    float v = y1[k];
    p0 = fmaf(W2[k],        v, p0);
    p1 = fmaf(W2[512 + k],  v, p1);
    p2 = fmaf(W2[1024 + k], v, p2);
  }
  #pragma unroll
  for (int m = 1; m < 64; m <<= 1) {
    p0 += __shfl_xor(p0, m);
    p1 += __shfl_xor(p1, m);
    p2 += __shfl_xor(p2, m);
  }
  if (l == 0) {
    float z0 = p0 + b2[0], z1 = p1 + b2[1], z2 = p2 + b2[2];
    float mx = fmaxf(z0, fmaxf(z1, z2));
    float lse = mx + logf(expf(z0 - mx) + expf(z1 - mx) + expf(z2 - mx));
    out[0] = z0 - lse; out[1] = z1 - lse; out[2] = z2 - lse;
  }
}

// ---------------- host ----------------
extern "C" void kernel_launch(void* const* d_in, const int* in_sizes, int n_in,
                              void* d_out, int out_size, void* d_ws, size_t ws_size,
                              hipStream_t stream)
{
  (void)in_sizes; (void)n_in; (void)out_size; (void)ws_size;
  const float* quote = (const float*)d_in[0];
  const float* Wih0  = (const float*)d_in[1];
  const float* Whh0  = (const float*)d_in[2];
  const float* bih0  = (const float*)d_in[3];
  const float* bhh0  = (const float*)d_in[4];
  const float* Wih1  = (const float*)d_in[5];
  const float* Whh1  = (const float*)d_in[6];
  const float* bih1  = (const float*)d_in[7];
  const float* bhh1  = (const float*)d_in[8];
  const float* W0    = (const float*)d_in[9];
  const float* b0    = (const float*)d_in[10];
  const float* W1    = (const float*)d_in[11];
  const float* b1    = (const float*)d_in[12];
  const float* W2    = (const float*)d_in[13];
  const float* b2    = (const float*)d_in[14];

  char* ws = (char*)d_ws;
  uint64* h1r    = (uint64*)(ws + 0);          // [16][1024] tagged fp32 (128 KB)
  uint64* h2r    = (uint64*)(ws + 131072);     // [4][1024]  tagged fp32 (32 KB)
  uint32* prog   = (uint32*)(ws + 163840);     // L1 progress watermark
  float*  h2last = (float*)(ws + 163968);      // 1024 f32
  float*  y0     = (float*)(ws + 168064);      // 512 f32
  float*  y1     = (float*)(ws + 170112);      // 512 f32

  hipMemsetAsync(ws, 0, 163968, stream);       // rings + prog zero each call

  (void)hipFuncSetAttribute((const void*)lstm_persistent,
                            hipFuncAttributeMaxDynamicSharedMemorySize, LDS_BYTES);

  void* args[] = { (void*)&quote, (void*)&Wih0, (void*)&Whh0, (void*)&bih0, (void*)&bhh0,
                   (void*)&Wih1, (void*)&Whh1, (void*)&bih1, (void*)&bhh1,
                   (void*)&h1r, (void*)&h2r, (void*)&prog, (void*)&h2last };
  (void)hipLaunchCooperativeKernel((const void*)lstm_persistent, dim3(256), dim3(256),
                                   args, (uint32)LDS_BYTES, stream);

  head_fc<<<512, 256, 0, stream>>>(W0, b0, h2last, y0, 1024);
  head_fc<<<512, 256, 0, stream>>>(W1, b1, y0, y1, 512);
  head_out<<<1, 64, 0, stream>>>(W2, b2, y1, (float*)d_out);
}

// Round 11
// 50853.433 us; speedup vs baseline: 36.2147x; 1.2921x over previous
//
#include <hip/hip_runtime.h>
#include <stdint.h>

typedef unsigned int uint32;
typedef unsigned long long uint64;

#define T_SEQ 8192

// ---------------- ws layout (R2 proved >=67MB usable; we use ~27.7MB) ----------------
#define WO_WHH0  0ull          // [4096][1024] bf16
#define WO_WIH0  8388608ull    // [4096][304]  bf16 (300 padded to 304)
#define WO_WHH1  10878976ull   // [4096][1024] bf16
#define WO_WIH1  19267584ull   // [4096][1024] bf16
#define WO_B0    27656192ull   // [4096] f32  (bih0+bhh0)
#define WO_B1    27672576ull   // [4096] f32
#define WO_H1    27688960ull   // [2][1024] f32 (parity t&1)
#define WO_H2    27697152ull   // [2][1024] f32 (parity s&1)
#define WO_CST0  27705344ull   // [1024] f32
#define WO_CST1  27709440ull   // [1024] f32
#define WO_Y0    27713536ull   // [512] f32
#define WO_Y1    27715584ull   // [512] f32

// ---------------- helpers ----------------
__device__ __forceinline__ float bflo(uint32 u){ return __uint_as_float(u << 16); }
__device__ __forceinline__ float bfhi(uint32 u){ return __uint_as_float(u & 0xffff0000u); }

__device__ __forceinline__ unsigned short f2bf(float f){
  uint32 u = __float_as_uint(f);
  u += 0x7fffu + ((u >> 16) & 1u);          // round-to-nearest-even
  return (unsigned short)(u >> 16);
}

__device__ __forceinline__ void mac8(float& a, uint4 w,
    float h0,float h1,float h2,float h3,float h4,float h5,float h6,float h7){
  a = fmaf(bflo(w.x), h0, a); a = fmaf(bfhi(w.x), h1, a);
  a = fmaf(bflo(w.y), h2, a); a = fmaf(bfhi(w.y), h3, a);
  a = fmaf(bflo(w.z), h4, a); a = fmaf(bfhi(w.z), h5, a);
  a = fmaf(bflo(w.w), h6, a); a = fmaf(bfhi(w.w), h7, a);
}

// ---------------- one-time per call: weights fp32 -> bf16 + bias sums ----------------
extern "C" __global__ void __launch_bounds__(256)
prep_weights(const float* __restrict__ Wih0, const float* __restrict__ Whh0,
             const float* __restrict__ bih0, const float* __restrict__ bhh0,
             const float* __restrict__ Wih1, const float* __restrict__ Whh1,
             const float* __restrict__ bih1, const float* __restrict__ bhh1,
             char* __restrict__ ws)
{
  unsigned short* whh0b = (unsigned short*)(ws + WO_WHH0);
  unsigned short* wih0b = (unsigned short*)(ws + WO_WIH0);
  unsigned short* whh1b = (unsigned short*)(ws + WO_WHH1);
  unsigned short* wih1b = (unsigned short*)(ws + WO_WIH1);
  float* b0 = (float*)(ws + WO_B0);
  float* b1 = (float*)(ws + WO_B1);

  const int stride = gridDim.x * blockDim.x;
  const int tid0 = blockIdx.x * blockDim.x + threadIdx.x;

  for (int i = tid0; i < 4096*1024; i += stride) whh0b[i] = f2bf(Whh0[i]);
  for (int i = tid0; i < 4096*1024; i += stride) whh1b[i] = f2bf(Whh1[i]);
  for (int i = tid0; i < 4096*1024; i += stride) wih1b[i] = f2bf(Wih1[i]);
  for (int i = tid0; i < 4096*304;  i += stride) {
    int r = i / 304, x = i - r * 304;
    wih0b[i] = f2bf(x < 300 ? Wih0[(size_t)r * 300 + x] : 0.0f);
  }
  for (int i = tid0; i < 4096; i += stride) {
    b0[i] = bih0[i] + bhh0[i];
    b1[i] = bih1[i] + bhh1[i];
  }
}

// ---------------- per-step kernel: node t = L0 step t + L1 step t-1 ----------------
// 256 WGs x 256 thr. Blocks 0..127: layer0 step t (skip if t>=T_SEQ); blocks
// 128..255: layer1 step t-1 (skip if t==0). All state in ws via PLAIN loads/
// stores — the kernel boundary is the global release/acquire (no polls, no
// atomics, no races). Per WG: 8 units; wave wv owns units 2wv,2wv+1 (rows
// g*1024+u); full 64-lane butterfly; lanes 0,1 compute gates + state update.
extern "C" __global__ void __launch_bounds__(256)
lstm_step(int t, const float* __restrict__ quote, char* __restrict__ ws)
{
  const unsigned short* whh0b = (const unsigned short*)(ws + WO_WHH0);
  const unsigned short* wih0b = (const unsigned short*)(ws + WO_WIH0);
  const unsigned short* whh1b = (const unsigned short*)(ws + WO_WHH1);
  const unsigned short* wih1b = (const unsigned short*)(ws + WO_WIH1);
  const float* b0 = (const float*)(ws + WO_B0);
  const float* b1 = (const float*)(ws + WO_B1);
  float* h1buf = (float*)(ws + WO_H1);
  float* h2buf = (float*)(ws + WO_H2);
  float* cst0  = (float*)(ws + WO_CST0);
  float* cst1  = (float*)(ws + WO_CST1);

  const int tid = threadIdx.x;
  const int wv  = tid >> 6;          // 0..3
  const int c   = tid & 63;

  float acc[8];
  #pragma unroll
  for (int i = 0; i < 8; ++i) acc[i] = 0.0f;

  if (blockIdx.x < 128) {
    // ========================= layer 0, step t =========================
    if (t >= T_SEQ) return;
    const int uA = (int)blockIdx.x * 8 + 2 * wv;   // wave's units uA, uA+1

    if (c < 38) {                                  // x-part
      float xv[8];
      int x0 = c << 3;
      const float* xr = quote + (size_t)t * 300;
      #pragma unroll
      for (int m = 0; m < 8; ++m) xv[m] = (x0 + m < 300) ? xr[x0 + m] : 0.0f;
      #pragma unroll
      for (int g = 0; g < 4; ++g)
        #pragma unroll
        for (int j = 0; j < 2; ++j) {
          int row = (g << 10) + uA + j;
          uint4 w = *(const uint4*)(wih0b + (size_t)row * 304 + (c << 3));
          mac8(acc[g*2+j], w, xv[0],xv[1],xv[2],xv[3],xv[4],xv[5],xv[6],xv[7]);
        }
    }
    if (t > 0) {                                   // h-part: h1[t-1]
      const float* hb = h1buf + (size_t)((t - 1) & 1) * 1024;
      float hv[16];
      #pragma unroll
      for (int k = 0; k < 16; ++k) hv[k] = hb[(c << 4) + k];
      #pragma unroll
      for (int g = 0; g < 4; ++g)
        #pragma unroll
        for (int j = 0; j < 2; ++j) {
          int row = (g << 10) + uA + j;
          const uint4* wp = (const uint4*)(whh0b + (size_t)row * 1024 + (c << 4));
          uint4 w0 = wp[0], w1 = wp[1];
          mac8(acc[g*2+j], w0, hv[0],hv[1],hv[2],hv[3],hv[4],hv[5],hv[6],hv[7]);
          mac8(acc[g*2+j], w1, hv[8],hv[9],hv[10],hv[11],hv[12],hv[13],hv[14],hv[15]);
        }
    }
    #pragma unroll
    for (int i = 0; i < 8; ++i) {                  // full butterfly
      #pragma unroll
      for (int m = 1; m < 64; m <<= 1) acc[i] += __shfl_xor(acc[i], m);
    }
    if (c < 2) {                                   // gates + state (lane c = unit uA+c)
      const int u = uA + c;
      float pre[4];
      #pragma unroll
      for (int g = 0; g < 4; ++g) pre[g] = acc[g*2 + c] + b0[(g << 10) + u];
      float ig = 1.0f/(1.0f+expf(-pre[0])), fg = 1.0f/(1.0f+expf(-pre[1]));
      float gg = tanhf(pre[2]),             og = 1.0f/(1.0f+expf(-pre[3]));
      float cs = fg * cst0[u] + ig * gg;
      cst0[u] = cs;
      h1buf[(size_t)(t & 1) * 1024 + u] = og * tanhf(cs);
    }
  } else {
    // ========================= layer 1, step s = t-1 =========================
    const int s = t - 1;
    if (s < 0) return;
    const int uA = ((int)blockIdx.x - 128) * 8 + 2 * wv;

    {                                              // Wih1 * h1[s]
      const float* hb = h1buf + (size_t)(s & 1) * 1024;
      float hv[16];
      #pragma unroll
      for (int k = 0; k < 16; ++k) hv[k] = hb[(c << 4) + k];
      #pragma unroll
      for (int g = 0; g < 4; ++g)
        #pragma unroll
        for (int j = 0; j < 2; ++j) {
          int row = (g << 10) + uA + j;
          const uint4* wp = (const uint4*)(wih1b + (size_t)row * 1024 + (c << 4));
          uint4 w0 = wp[0], w1 = wp[1];
          mac8(acc[g*2+j], w0, hv[0],hv[1],hv[2],hv[3],hv[4],hv[5],hv[6],hv[7]);
          mac8(acc[g*2+j], w1, hv[8],hv[9],hv[10],hv[11],hv[12],hv[13],hv[14],hv[15]);
        }
    }
    if (s > 0) {                                   // Whh1 * h2[s-1]
      const float* hb = h2buf + (size_t)((s - 1) & 1) * 1024;
      float hv[16];
      #pragma unroll
      for (int k = 0; k < 16; ++k) hv[k] = hb[(c << 4) + k];
      #pragma unroll
      for (int g = 0; g < 4; ++g)
        #pragma unroll
        for (int j = 0; j < 2; ++j) {
          int row = (g << 10) + uA + j;
          const uint4* wp = (const uint4*)(whh1b + (size_t)row * 1024 + (c << 4));
          uint4 w0 = wp[0], w1 = wp[1];
          mac8(acc[g*2+j], w0, hv[0],hv[1],hv[2],hv[3],hv[4],hv[5],hv[6],hv[7]);
          mac8(acc[g*2+j], w1, hv[8],hv[9],hv[10],hv[11],hv[12],hv[13],hv[14],hv[15]);
        }
    }
    #pragma unroll
    for (int i = 0; i < 8; ++i) {
      #pragma unroll
      for (int m = 1; m < 64; m <<= 1) acc[i] += __shfl_xor(acc[i], m);
    }
    if (c < 2) {
      const int u = uA + c;
      float pre[4];
      #pragma unroll
      for (int g = 0; g < 4; ++g) pre[g] = acc[g*2 + c] + b1[(g << 10) + u];
      float ig = 1.0f/(1.0f+expf(-pre[0])), fg = 1.0f/(1.0f+expf(-pre[1]));
      float gg = tanhf(pre[2]),             og = 1.0f/(1.0f+expf(-pre[3]));
      float cs = fg * cst1[u] + ig * gg;
      cst1[u] = cs;
      h2buf[(size_t)(s & 1) * 1024 + u] = og * tanhf(cs);
    }
  }
}

// ---------------- tiny MLP head ----------------
extern "C" __global__ void __launch_bounds__(256)
head_fc(const float* __restrict__ W, const float* __restrict__ b,
        const float* __restrict__ xin, float* __restrict__ y, int n_in)
{
  __shared__ float sred[256];
  const int i = blockIdx.x;
  float p = 0.0f;
  for (int k = threadIdx.x; k < n_in; k += 256)
    p = fmaf(W[(size_t)i * n_in + k], xin[k], p);
  sred[threadIdx.x] = p;
  __syncthreads();
  for (int s = 128; s > 0; s >>= 1) {
    if (threadIdx.x < s) sred[threadIdx.x] += sred[threadIdx.x + s];
    __syncthreads();
  }
  if (threadIdx.x == 0) y[i] = fmaxf(sred[0] + b[i], 0.0f);
}

extern "C" __global__ void __launch_bounds__(64)
head_out(const float* __restrict__ W2, const float* __restrict__ b2,
         const float* __restrict__ y1, float* __restrict__ out)
{
  const int l = threadIdx.x;
  float p0 = 0.0f, p1 = 0.0f, p2 = 0.0f;
  for (int k = l; k < 512; k += 64) {
    float v = y1[k];
    p0 = fmaf(W2[k],        v, p0);
    p1 = fmaf(W2[512 + k],  v, p1);
    p2 = fmaf(W2[1024 + k], v, p2);
  }
  #pragma unroll
  for (int m = 1; m < 64; m <<= 1) {
    p0 += __shfl_xor(p0, m);
    p1 += __shfl_xor(p1, m);
    p2 += __shfl_xor(p2, m);
  }
  if (l == 0) {
    float z0 = p0 + b2[0], z1 = p1 + b2[1], z2 = p2 + b2[2];
    float mx = fmaxf(z0, fmaxf(z1, z2));
    float lse = mx + logf(expf(z0 - mx) + expf(z1 - mx) + expf(z2 - mx));
    out[0] = z0 - lse; out[1] = z1 - lse; out[2] = z2 - lse;
  }
}

// ---------------- host ----------------
extern "C" void kernel_launch(void* const* d_in, const int* in_sizes, int n_in,
                              void* d_out, int out_size, void* d_ws, size_t ws_size,
                              hipStream_t stream)
{
  (void)in_sizes; (void)n_in; (void)out_size; (void)ws_size;
  const float* quote = (const float*)d_in[0];
  const float* Wih0  = (const float*)d_in[1];
  const float* Whh0  = (const float*)d_in[2];
  const float* bih0  = (const float*)d_in[3];
  const float* bhh0  = (const float*)d_in[4];
  const float* Wih1  = (const float*)d_in[5];
  const float* Whh1  = (const float*)d_in[6];
  const float* bih1  = (const float*)d_in[7];
  const float* bhh1  = (const float*)d_in[8];
  const float* W0    = (const float*)d_in[9];
  const float* b0    = (const float*)d_in[10];
  const float* W1    = (const float*)d_in[11];
  const float* b1    = (const float*)d_in[12];
  const float* W2    = (const float*)d_in[13];
  const float* b2    = (const float*)d_in[14];

  char* ws = (char*)d_ws;
  float* h2buf = (float*)(ws + WO_H2);
  float* y0    = (float*)(ws + WO_Y0);
  float* y1    = (float*)(ws + WO_Y1);

  // cell states must be zero at every call start
  hipMemsetAsync(ws + WO_CST0, 0, 8192, stream);

  prep_weights<<<2048, 256, 0, stream>>>(Wih0, Whh0, bih0, bhh0,
                                         Wih1, Whh1, bih1, bhh1, ws);

  // node t: L0 step t (blocks 0..127) + L1 step t-1 (blocks 128..255)
  for (int t = 0; t <= T_SEQ; ++t)
    lstm_step<<<256, 256, 0, stream>>>(t, quote, ws);

  // h2[T-1] is at parity (8191 & 1) = 1
  head_fc<<<512, 256, 0, stream>>>(W0, b0, h2buf + 1024, y0, 1024);
  head_fc<<<512, 256, 0, stream>>>(W1, b1, y0, y1, 512);
  head_out<<<1, 64, 0, stream>>>(W2, b2, y1, (float*)d_out);
}

// Round 12
// 41997.189 us; speedup vs baseline: 43.8516x; 1.2109x over previous
//
#include <hip/hip_runtime.h>
#include <stdint.h>

typedef unsigned int uint32;
typedef unsigned long long uint64;

#define T_SEQ 8192

// ---------------- ws layout (~27.7MB) ----------------
#define WO_WHH0  0ull          // [4096][1024] bf16
#define WO_WIH0  8388608ull    // [4096][304]  bf16 (300 padded to 304)
#define WO_WHH1  10878976ull   // [4096][1024] bf16
#define WO_WIH1  19267584ull   // [4096][1024] bf16
#define WO_B0    27656192ull   // [4096] f32  (bih0+bhh0)
#define WO_B1    27672576ull   // [4096] f32
#define WO_H1    27688960ull   // [2][1024] f32 (parity t&1)
#define WO_H2    27697152ull   // [2][1024] f32 (parity s&1)
#define WO_CST0  27705344ull   // [1024] f32
#define WO_CST1  27709440ull   // [1024] f32
#define WO_Y0    27713536ull   // [512] f32
#define WO_Y1    27715584ull   // [512] f32

// ---------------- helpers ----------------
__device__ __forceinline__ float bflo(uint32 u){ return __uint_as_float(u << 16); }
__device__ __forceinline__ float bfhi(uint32 u){ return __uint_as_float(u & 0xffff0000u); }

__device__ __forceinline__ unsigned short f2bf(float f){
  uint32 u = __float_as_uint(f);
  u += 0x7fffu + ((u >> 16) & 1u);          // round-to-nearest-even
  return (unsigned short)(u >> 16);
}

__device__ __forceinline__ void mac8(float& a, uint4 w,
    float h0,float h1,float h2,float h3,float h4,float h5,float h6,float h7){
  a = fmaf(bflo(w.x), h0, a); a = fmaf(bfhi(w.x), h1, a);
  a = fmaf(bflo(w.y), h2, a); a = fmaf(bfhi(w.y), h3, a);
  a = fmaf(bflo(w.z), h4, a); a = fmaf(bfhi(w.z), h5, a);
  a = fmaf(bflo(w.w), h6, a); a = fmaf(bfhi(w.w), h7, a);
}

// ---------------- one-time per call: weights fp32 -> bf16 + bias sums ----------------
extern "C" __global__ void __launch_bounds__(256)
prep_weights(const float* __restrict__ Wih0, const float* __restrict__ Whh0,
             const float* __restrict__ bih0, const float* __restrict__ bhh0,
             const float* __restrict__ Wih1, const float* __restrict__ Whh1,
             const float* __restrict__ bih1, const float* __restrict__ bhh1,
             char* __restrict__ ws)
{
  unsigned short* whh0b = (unsigned short*)(ws + WO_WHH0);
  unsigned short* wih0b = (unsigned short*)(ws + WO_WIH0);
  unsigned short* whh1b = (unsigned short*)(ws + WO_WHH1);
  unsigned short* wih1b = (unsigned short*)(ws + WO_WIH1);
  float* b0 = (float*)(ws + WO_B0);
  float* b1 = (float*)(ws + WO_B1);

  const int stride = gridDim.x * blockDim.x;
  const int tid0 = blockIdx.x * blockDim.x + threadIdx.x;

  for (int i = tid0; i < 4096*1024; i += stride) whh0b[i] = f2bf(Whh0[i]);
  for (int i = tid0; i < 4096*1024; i += stride) whh1b[i] = f2bf(Whh1[i]);
  for (int i = tid0; i < 4096*1024; i += stride) wih1b[i] = f2bf(Wih1[i]);
  for (int i = tid0; i < 4096*304;  i += stride) {
    int r = i / 304, x = i - r * 304;
    wih0b[i] = f2bf(x < 300 ? Wih0[(size_t)r * 300 + x] : 0.0f);
  }
  for (int i = tid0; i < 4096; i += stride) {
    b0[i] = bih0[i] + bhh0[i];
    b1[i] = bih1[i] + bhh1[i];
  }
}

// ---------------- per-step kernel: node t = L0 step t + L1 step t-1 ----------------
// 512 WGs x 256 thr (2 WG/CU, 8 waves/CU). Blocks 0..255: layer0 step t; blocks
// 256..511: layer1 step t-1. Each WG owns 4 units; wave wv owns ONE unit
// (4 gate rows x 1024 cols = 8KB bf16). All state in ws via PLAIN loads/stores —
// the kernel boundary is the global release/acquire (no polls, no atomics).
// Full 64-lane butterfly -> lane 0 holds all 4 gate sums -> gates + state update.
extern "C" __global__ void __launch_bounds__(256)
lstm_step(int t, const float* __restrict__ quote, char* __restrict__ ws)
{
  const unsigned short* whh0b = (const unsigned short*)(ws + WO_WHH0);
  const unsigned short* wih0b = (const unsigned short*)(ws + WO_WIH0);
  const unsigned short* whh1b = (const unsigned short*)(ws + WO_WHH1);
  const unsigned short* wih1b = (const unsigned short*)(ws + WO_WIH1);
  const float* b0 = (const float*)(ws + WO_B0);
  const float* b1 = (const float*)(ws + WO_B1);
  float* h1buf = (float*)(ws + WO_H1);
  float* h2buf = (float*)(ws + WO_H2);
  float* cst0  = (float*)(ws + WO_CST0);
  float* cst1  = (float*)(ws + WO_CST1);

  const int tid = threadIdx.x;
  const int wv  = tid >> 6;          // 0..3
  const int c   = tid & 63;

  float acc[4];
  #pragma unroll
  for (int i = 0; i < 4; ++i) acc[i] = 0.0f;

  if (blockIdx.x < 256) {
    // ========================= layer 0, step t =========================
    if (t >= T_SEQ) return;
    const int u = (int)blockIdx.x * 4 + wv;        // this wave's unit

    if (c < 38) {                                  // x-part
      float xv[8];
      int x0 = c << 3;
      const float* xr = quote + (size_t)t * 300;
      #pragma unroll
      for (int m = 0; m < 8; ++m) xv[m] = (x0 + m < 300) ? xr[x0 + m] : 0.0f;
      #pragma unroll
      for (int g = 0; g < 4; ++g) {
        int row = (g << 10) + u;
        uint4 w = *(const uint4*)(wih0b + (size_t)row * 304 + (c << 3));
        mac8(acc[g], w, xv[0],xv[1],xv[2],xv[3],xv[4],xv[5],xv[6],xv[7]);
      }
    }
    if (t > 0) {                                   // h-part: h1[t-1]
      const float* hb = h1buf + (size_t)((t - 1) & 1) * 1024;
      float hv[16];
      #pragma unroll
      for (int k = 0; k < 16; ++k) hv[k] = hb[(c << 4) + k];
      #pragma unroll
      for (int g = 0; g < 4; ++g) {
        int row = (g << 10) + u;
        const uint4* wp = (const uint4*)(whh0b + (size_t)row * 1024 + (c << 4));
        uint4 w0 = wp[0], w1 = wp[1];
        mac8(acc[g], w0, hv[0],hv[1],hv[2],hv[3],hv[4],hv[5],hv[6],hv[7]);
        mac8(acc[g], w1, hv[8],hv[9],hv[10],hv[11],hv[12],hv[13],hv[14],hv[15]);
      }
    }
    #pragma unroll
    for (int i = 0; i < 4; ++i) {                  // full butterfly
      #pragma unroll
      for (int m = 1; m < 64; m <<= 1) acc[i] += __shfl_xor(acc[i], m);
    }
    if (c == 0) {                                  // gates + state update
      float pre[4];
      #pragma unroll
      for (int g = 0; g < 4; ++g) pre[g] = acc[g] + b0[(g << 10) + u];
      float ig = 1.0f/(1.0f+expf(-pre[0])), fg = 1.0f/(1.0f+expf(-pre[1]));
      float gg = tanhf(pre[2]),             og = 1.0f/(1.0f+expf(-pre[3]));
      float cs = fg * cst0[u] + ig * gg;
      cst0[u] = cs;
      h1buf[(size_t)(t & 1) * 1024 + u] = og * tanhf(cs);
    }
  } else {
    // ========================= layer 1, step s = t-1 =========================
    const int s = t - 1;
    if (s < 0) return;
    const int u = ((int)blockIdx.x - 256) * 4 + wv;

    {                                              // Wih1 * h1[s]
      const float* hb = h1buf + (size_t)(s & 1) * 1024;
      float hv[16];
      #pragma unroll
      for (int k = 0; k < 16; ++k) hv[k] = hb[(c << 4) + k];
      #pragma unroll
      for (int g = 0; g < 4; ++g) {
        int row = (g << 10) + u;
        const uint4* wp = (const uint4*)(wih1b + (size_t)row * 1024 + (c << 4));
        uint4 w0 = wp[0], w1 = wp[1];
        mac8(acc[g], w0, hv[0],hv[1],hv[2],hv[3],hv[4],hv[5],hv[6],hv[7]);
        mac8(acc[g], w1, hv[8],hv[9],hv[10],hv[11],hv[12],hv[13],hv[14],hv[15]);
      }
    }
    if (s > 0) {                                   // Whh1 * h2[s-1]
      const float* hb = h2buf + (size_t)((s - 1) & 1) * 1024;
      float hv[16];
      #pragma unroll
      for (int k = 0; k < 16; ++k) hv[k] = hb[(c << 4) + k];
      #pragma unroll
      for (int g = 0; g < 4; ++g) {
        int row = (g << 10) + u;
        const uint4* wp = (const uint4*)(whh1b + (size_t)row * 1024 + (c << 4));
        uint4 w0 = wp[0], w1 = wp[1];
        mac8(acc[g], w0, hv[0],hv[1],hv[2],hv[3],hv[4],hv[5],hv[6],hv[7]);
        mac8(acc[g], w1, hv[8],hv[9],hv[10],hv[11],hv[12],hv[13],hv[14],hv[15]);
      }
    }
    #pragma unroll
    for (int i = 0; i < 4; ++i) {
      #pragma unroll
      for (int m = 1; m < 64; m <<= 1) acc[i] += __shfl_xor(acc[i], m);
    }
    if (c == 0) {
      float pre[4];
      #pragma unroll
      for (int g = 0; g < 4; ++g) pre[g] = acc[g] + b1[(g << 10) + u];
      float ig = 1.0f/(1.0f+expf(-pre[0])), fg = 1.0f/(1.0f+expf(-pre[1]));
      float gg = tanhf(pre[2]),             og = 1.0f/(1.0f+expf(-pre[3]));
      float cs = fg * cst1[u] + ig * gg;
      cst1[u] = cs;
      h2buf[(size_t)(s & 1) * 1024 + u] = og * tanhf(cs);
    }
  }
}

// ---------------- tiny MLP head ----------------
extern "C" __global__ void __launch_bounds__(256)
head_fc(const float* __restrict__ W, const float* __restrict__ b,
        const float* __restrict__ xin, float* __restrict__ y, int n_in)
{
  __shared__ float sred[256];
  const int i = blockIdx.x;
  float p = 0.0f;
  for (int k = threadIdx.x; k < n_in; k += 256)
    p = fmaf(W[(size_t)i * n_in + k], xin[k], p);
  sred[threadIdx.x] = p;
  __syncthreads();
  for (int s = 128; s > 0; s >>= 1) {
    if (threadIdx.x < s) sred[threadIdx.x] += sred[threadIdx.x + s];
    __syncthreads();
  }
  if (threadIdx.x == 0) y[i] = fmaxf(sred[0] + b[i], 0.0f);
}

extern "C" __global__ void __launch_bounds__(64)
head_out(const float* __restrict__ W2, const float* __restrict__ b2,
         const float* __restrict__ y1, float* __restrict__ out)
{
  const int l = threadIdx.x;
  float p0 = 0.0f, p1 = 0.0f, p2 = 0.0f;
  for (int k = l; k < 512; k += 64) {
    float v = y1[k];
    p0 = fmaf(W2[k],        v, p0);
    p1 = fmaf(W2[512 + k],  v, p1);
    p2 = fmaf(W2[1024 + k], v, p2);
  }
  #pragma unroll
  for (int m = 1; m < 64; m <<= 1) {
    p0 += __shfl_xor(p0, m);
    p1 += __shfl_xor(p1, m);
    p2 += __shfl_xor(p2, m);
  }
  if (l == 0) {
    float z0 = p0 + b2[0], z1 = p1 + b2[1], z2 = p2 + b2[2];
    float mx = fmaxf(z0, fmaxf(z1, z2));
    float lse = mx + logf(expf(z0 - mx) + expf(z1 - mx) + expf(z2 - mx));
    out[0] = z0 - lse; out[1] = z1 - lse; out[2] = z2 - lse;
  }
}

// ---------------- host ----------------
extern "C" void kernel_launch(void* const* d_in, const int* in_sizes, int n_in,
                              void* d_out, int out_size, void* d_ws, size_t ws_size,
                              hipStream_t stream)
{
  (void)in_sizes; (void)n_in; (void)out_size; (void)ws_size;
  const float* quote = (const float*)d_in[0];
  const float* Wih0  = (const float*)d_in[1];
  const float* Whh0  = (const float*)d_in[2];
  const float* bih0  = (const float*)d_in[3];
  const float* bhh0  = (const float*)d_in[4];
  const float* Wih1  = (const float*)d_in[5];
  const float* Whh1  = (const float*)d_in[6];
  const float* bih1  = (const float*)d_in[7];
  const float* bhh1  = (const float*)d_in[8];
  const float* W0    = (const float*)d_in[9];
  const float* b0    = (const float*)d_in[10];
  const float* W1    = (const float*)d_in[11];
  const float* b1    = (const float*)d_in[12];
  const float* W2    = (const float*)d_in[13];
  const float* b2    = (const float*)d_in[14];

  char* ws = (char*)d_ws;
  float* h2buf = (float*)(ws + WO_H2);
  float* y0    = (float*)(ws + WO_Y0);
  float* y1    = (float*)(ws + WO_Y1);

  // cell states must be zero at every call start
  hipMemsetAsync(ws + WO_CST0, 0, 8192, stream);

  prep_weights<<<2048, 256, 0, stream>>>(Wih0, Whh0, bih0, bhh0,
                                         Wih1, Whh1, bih1, bhh1, ws);

  // node t: L0 step t (blocks 0..255) + L1 step t-1 (blocks 256..511)
  for (int t = 0; t <= T_SEQ; ++t)
    lstm_step<<<512, 256, 0, stream>>>(t, quote, ws);

  // h2[T-1] is at parity (8191 & 1) = 1
  head_fc<<<512, 256, 0, stream>>>(W0, b0, h2buf + 1024, y0, 1024);
  head_fc<<<512, 256, 0, stream>>>(W1, b1, y0, y1, 512);
  head_out<<<1, 64, 0, stream>>>(W2, b2, y1, (float*)d_out);
}